// Round 5
// baseline (1254.938 us; speedup 1.0000x reference)
//
#include <hip/hip_runtime.h>

// B=32, N_IN=2048, K_OUT=128, C=16, D=16, 3 routing iters.
// Packed path:
//   k_packX   : x -> per-lane MFMA A-frags (hi/lo)
//   k_packWacc: W -> per-lane B-frags (Wp) + iter-0 unweighted MFMA accumulation fused.
//   k_iter    : FUSED logits+acc per routing iter. Block=16 waves(1024thr), wave=8 k x 2 bg,
//               block=8 i's, grid=256 (1 block/CU). Per i: sub-A computes u+e (e->LDS),
//               2-barrier denom reduction over 128 k, sub-B recomputes u (Wp re-read is
//               L2-warm, 128KB/i working set) and register-accumulates p*u. No pbuf.
//   k_fin     : partial-reduce (nslice param: 64 for iter0, 256 for k_iter) + squash.
// MFMA hi/lo trick: K=32 packed [c_hi | c_lo] -> 2 MFMAs give ~exact fp32 product.
// Swapped operands (verified R2): u[d][b] = mfma(Wfrag, xfrag); d-reduce = 4 in-lane
// fmas + xor16 + xor32. No atomics anywhere.
// V table stored [k][d>>2][b][d&3] so each lane's 4 d-values load as one float4.
// NOTE: second __launch_bounds__ arg is forbidden (hard VGPR cap -> scratch spills).
// k_iter uses single-arg __launch_bounds__(1024) (=> VGPR<=128, guaranteed launchable).

typedef __attribute__((ext_vector_type(8))) short  s16x8;
typedef __attribute__((ext_vector_type(4))) float  f32x4;

__device__ __forceinline__ unsigned bf16rn(float f) {
    const unsigned u = __builtin_bit_cast(unsigned, f);
    return (u + 0x7fffu + ((u >> 16) & 1u)) >> 16;
}
__device__ __forceinline__ unsigned pack2rn(float a, float b) {
    return bf16rn(a) | (bf16rn(b) << 16);
}
__device__ __forceinline__ unsigned phi(float a, float b) {
    return (__builtin_bit_cast(unsigned, a) >> 16) | (__builtin_bit_cast(unsigned, b) & 0xffff0000u);
}
__device__ __forceinline__ unsigned plo(float a, float b) {
    const float la = a - __builtin_bit_cast(float, __builtin_bit_cast(unsigned, a) & 0xffff0000u);
    const float lb = b - __builtin_bit_cast(float, __builtin_bit_cast(unsigned, b) & 0xffff0000u);
    return pack2rn(la, lb);
}

__device__ __forceinline__ void pack_A(const float* __restrict__ xp, s16x8& A1, s16x8& A2) {
    const float4 x0 = *(const float4*)xp;
    const float4 x1 = *(const float4*)(xp + 4);
    uint4 h, l;
    h.x = phi(x0.x, x0.y); h.y = phi(x0.z, x0.w);
    h.z = phi(x1.x, x1.y); h.w = phi(x1.z, x1.w);
    l.x = plo(x0.x, x0.y); l.y = plo(x0.z, x0.w);
    l.z = plo(x1.x, x1.y); l.w = plo(x1.z, x1.w);
    A1 = __builtin_bit_cast(s16x8, h);
    A2 = __builtin_bit_cast(s16x8, l);
}

__device__ __forceinline__ s16x8 pack_B_f(const float4 w0, const float4 w1, bool sel) {
    const float f[8] = {w0.x, w0.y, w0.z, w0.w, w1.x, w1.y, w1.z, w1.w};
    float t[8];
#pragma unroll
    for (int j = 0; j < 8; ++j) {
        const float hf = __builtin_bit_cast(float, __builtin_bit_cast(unsigned, f[j]) & 0xffff0000u);
        t[j] = sel ? hf : (f[j] - hf);
    }
    uint4 bw;
    bw.x = pack2rn(t[0], t[1]);
    bw.y = pack2rn(t[2], t[3]);
    bw.z = pack2rn(t[4], t[5]);
    bw.w = pack2rn(t[6], t[7]);
    return __builtin_bit_cast(s16x8, bw);
}
__device__ __forceinline__ s16x8 pack_B(const float* __restrict__ wp, bool sel) {
    return pack_B_f(*(const float4*)wp, *(const float4*)(wp + 4), sel);
}

// ---------------------------------------------------------------------------
__global__ __launch_bounds__(256) void k_packX(const float* __restrict__ x,
                                               s16x8* __restrict__ xA)
{
    const int wid  = blockIdx.x * 4 + (threadIdx.x >> 6);   // 0..4095 = i*2+bg
    const int lane = threadIdx.x & 63;
    const int i  = wid >> 1, bg = wid & 1;
    const int n  = lane & 15, q = lane >> 4;
    const int oct = (q & 1) * 8;
    s16x8 A1, A2;
    pack_A(x + ((size_t)(bg * 16 + n) * 2048 + i) * 16 + oct, A1, A2);
    s16x8* o = xA + ((size_t)wid * 64 + lane) * 2;
    o[0] = A1;
    o[1] = A2;
}

// ---------------------------------------------------------------------------
// Fused W-pack + iter0 accumulation (64 slices of 32 i). Software-pipelined.
__global__ __launch_bounds__(256) void k_packWacc(const float* __restrict__ W,
                                                  const s16x8* __restrict__ xA,
                                                  s16x8* __restrict__ Wp,
                                                  float* __restrict__ out_sl)   // [64][b][k][d]
{
    const int w    = blockIdx.x * 4 + (threadIdx.x >> 6);   // 0..4095
    const int lane = threadIdx.x & 63;
    const int n    = lane & 15;
    const int q    = lane >> 4;
    const int oct  = (q & 1) * 8;
    const bool sel = (q < 2);
    const int k0    = (w & 63) * 2;
    const int slice = w >> 6;
    const int i0    = slice * 32;

    const f32x4 zero = {0.f, 0.f, 0.f, 0.f};
    f32x4 acc[2][2];
#pragma unroll
    for (int kp = 0; kp < 2; ++kp)
#pragma unroll
        for (int bg = 0; bg < 2; ++bg) acc[kp][bg] = zero;

    float4 rw0[2], rw1[2];
    s16x8 X1c[2], X2c[2];
    {
        const float* wp_ = W + (size_t)i0 * 32768 + (size_t)k0 * 256 + n * 16 + oct;
        rw0[0] = *(const float4*)wp_;          rw1[0] = *(const float4*)(wp_ + 4);
        rw0[1] = *(const float4*)(wp_ + 256);  rw1[1] = *(const float4*)(wp_ + 260);
        const s16x8* xp = xA + (size_t)i0 * 256 + (size_t)lane * 2;
        X1c[0] = xp[0];   X2c[0] = xp[1];
        X1c[1] = xp[128]; X2c[1] = xp[129];
    }

#pragma unroll 1
    for (int i = i0; i < i0 + 32; ++i) {
        const int in_ = (i + 1 < i0 + 32) ? i + 1 : i;
        float4 nw0[2], nw1[2];
        s16x8 X1n[2], X2n[2];
        {
            const float* wp_ = W + (size_t)in_ * 32768 + (size_t)k0 * 256 + n * 16 + oct;
            nw0[0] = *(const float4*)wp_;          nw1[0] = *(const float4*)(wp_ + 4);
            nw0[1] = *(const float4*)(wp_ + 256);  nw1[1] = *(const float4*)(wp_ + 260);
            const s16x8* xp = xA + (size_t)in_ * 256 + (size_t)lane * 2;
            X1n[0] = xp[0];   X2n[0] = xp[1];
            X1n[1] = xp[128]; X2n[1] = xp[129];
        }
#pragma unroll
        for (int kp = 0; kp < 2; ++kp) {
            const s16x8 Wf = pack_B_f(rw0[kp], rw1[kp], sel);
            Wp[((size_t)i * 128 + (k0 + kp)) * 64 + lane] = Wf;
#pragma unroll
            for (int bg = 0; bg < 2; ++bg) {
                acc[kp][bg] = __builtin_amdgcn_mfma_f32_16x16x32_bf16(Wf, X1c[bg], acc[kp][bg], 0, 0, 0);
                acc[kp][bg] = __builtin_amdgcn_mfma_f32_16x16x32_bf16(Wf, X2c[bg], acc[kp][bg], 0, 0, 0);
            }
        }
#pragma unroll
        for (int kp = 0; kp < 2; ++kp) { rw0[kp] = nw0[kp]; rw1[kp] = nw1[kp]; }
#pragma unroll
        for (int bg = 0; bg < 2; ++bg) { X1c[bg] = X1n[bg]; X2c[bg] = X2n[bg]; }
    }
#pragma unroll
    for (int kp = 0; kp < 2; ++kp)
#pragma unroll
        for (int bg = 0; bg < 2; ++bg)
            *(f32x4*)(out_sl + (((size_t)slice * 32 + bg * 16 + n) * 128 + (k0 + kp)) * 16 + 4 * q)
                = acc[kp][bg];
}

// ---------------------------------------------------------------------------
// FUSED routing iteration: logits+softmax+weighted-accumulate in one pass over Wp.
// Block: 1024 thr = 16 waves; wave wv owns k in [wv*8, wv*8+8), both b-groups.
// Block owns i in [c*8, c*8+8). Writes out_sl[c][b][k][d] and csl[c][k][b].
__global__ __launch_bounds__(1024) void k_iter(const s16x8* __restrict__ Wp,
                                               const s16x8* __restrict__ xA,
                                               const float* __restrict__ Vq,   // [k][d>>2][b][d&3]
                                               const float* __restrict__ Nt,   // [k][b]
                                               const float T,
                                               float* __restrict__ out_sl,     // [256][b][k][d]
                                               float* __restrict__ csl)        // [256][k][b]
{
    __shared__ __align__(16) float e_s[16][8][32];
    __shared__ __align__(16) float den_s[16][32];
    __shared__ float denom_s[32];
    const int tid  = threadIdx.x;
    const int wv   = tid >> 6, lane = tid & 63;
    const int n    = lane & 15, q = lane >> 4;
    const int c     = blockIdx.x;        // chunk 0..255
    const int i0    = c * 8;
    const int kbase = wv * 8;
    const f32x4 zero = {0.f, 0.f, 0.f, 0.f};

    f32x4 acc[8][2];
    float cs0[2][2];                     // cs0[j][bg] holds colsum for kp = 2*q + j
#pragma unroll
    for (int kp = 0; kp < 8; ++kp)
#pragma unroll
        for (int bg = 0; bg < 2; ++bg) acc[kp][bg] = zero;
    cs0[0][0] = cs0[0][1] = cs0[1][0] = cs0[1][1] = 0.f;

#pragma unroll 1
    for (int ii = 0; ii < 8; ++ii) {
        const int i = i0 + ii;
        const s16x8* xp = xA + (size_t)i * 256 + (size_t)lane * 2;
        const s16x8 X1[2] = {xp[0], xp[128]};
        const s16x8 X2[2] = {xp[1], xp[129]};
        const s16x8* wrow = Wp + ((size_t)i * 128 + kbase) * 64 + lane;

        float den0 = 0.f, den1 = 0.f;
        // ---- sub-A: u + logits e (per-wave LDS rows; no cross-wave traffic) ----
#pragma unroll 2
        for (int kp = 0; kp < 8; ++kp) {
            const int k = kbase + kp;
            const s16x8 Wf = wrow[(size_t)kp * 64];
#pragma unroll
            for (int bg = 0; bg < 2; ++bg) {
                f32x4 u = __builtin_amdgcn_mfma_f32_16x16x32_bf16(Wf, X1[bg], zero, 0, 0, 0);
                u       = __builtin_amdgcn_mfma_f32_16x16x32_bf16(Wf, X2[bg], u,    0, 0, 0);
                const float4 Vv = *(const float4*)(Vq + (((size_t)k * 4 + q) * 32 + bg * 16 + n) * 4);
                float s2 = u.x * u.x;
                s2 = fmaf(u.y, u.y, s2);
                s2 = fmaf(u.z, u.z, s2);
                s2 = fmaf(u.w, u.w, s2);
                float dt = u.x * Vv.x;
                dt = fmaf(u.y, Vv.y, dt);
                dt = fmaf(u.z, Vv.z, dt);
                dt = fmaf(u.w, Vv.w, dt);
                s2 += __shfl_xor(s2, 16, 64);
                s2 += __shfl_xor(s2, 32, 64);
                dt += __shfl_xor(dt, 16, 64);
                dt += __shfl_xor(dt, 32, 64);
                const float Nr  = Nt[(size_t)k * 32 + bg * 16 + n];
                const float inv = 1.0f / (0.5f + s2);
                const float scl = sqrtf(s2) * inv;
                const float fq  = s2 * s2 * inv * inv;
                const float e   = __expf(T * (1.0f - fq) + 2.0f * scl * dt - Nr);
                if (bg == 0) den0 += e; else den1 += e;
                if (lane < 16) e_s[wv][kp][bg * 16 + n] = e;
            }
        }
        if (lane < 16) {
            den_s[wv][n]      = den0;
            den_s[wv][16 + n] = den1;
        }
        __syncthreads();
        if (tid < 32) {
            float s = 0.f;
#pragma unroll
            for (int w2 = 0; w2 < 16; ++w2) s += den_s[w2][tid];
            denom_s[tid] = s;
        }
        __syncthreads();
        const float inv0 = 1.0f / denom_s[n];
        const float inv1 = 1.0f / denom_s[16 + n];
        // ---- sub-B: recompute u (Wp L2-warm), accumulate p*u ----
#pragma unroll 2
        for (int kp = 0; kp < 8; ++kp) {
            const s16x8 Wf = wrow[(size_t)kp * 64];
#pragma unroll
            for (int bg = 0; bg < 2; ++bg) {
                f32x4 u = __builtin_amdgcn_mfma_f32_16x16x32_bf16(Wf, X1[bg], zero, 0, 0, 0);
                u       = __builtin_amdgcn_mfma_f32_16x16x32_bf16(Wf, X2[bg], u,    0, 0, 0);
                const float p = e_s[wv][kp][bg * 16 + n] * (bg == 0 ? inv0 : inv1);
                acc[kp][bg].x = fmaf(p, u.x, acc[kp][bg].x);
                acc[kp][bg].y = fmaf(p, u.y, acc[kp][bg].y);
                acc[kp][bg].z = fmaf(p, u.z, acc[kp][bg].z);
                acc[kp][bg].w = fmaf(p, u.w, acc[kp][bg].w);
                cs0[kp & 1][bg] += ((kp >> 1) == q) ? p : 0.f;
            }
        }
    }
#pragma unroll
    for (int kp = 0; kp < 8; ++kp)
#pragma unroll
        for (int bg = 0; bg < 2; ++bg)
            *(f32x4*)(out_sl + (((size_t)c * 32 + bg * 16 + n) * 128 + (kbase + kp)) * 16 + 4 * q)
                = acc[kp][bg];
#pragma unroll
    for (int j = 0; j < 2; ++j)
#pragma unroll
        for (int bg = 0; bg < 2; ++bg)
            csl[((size_t)c * 128 + kbase + 2 * q + j) * 32 + bg * 16 + n] = cs0[j][bg];
}

// ---------------------------------------------------------------------------
// Legacy unfused kernels (fallback path only; in-kernel packing).
template<bool USE_P>
__global__ __launch_bounds__(256) void k_acc_fb(const float* __restrict__ W,
                                                const float* __restrict__ x,
                                                const float* __restrict__ p,
                                                float* __restrict__ out_sl,
                                                float* __restrict__ csl)
{
    const int w    = blockIdx.x * 4 + (threadIdx.x >> 6);
    const int lane = threadIdx.x & 63;
    const int n    = lane & 15;
    const int q    = lane >> 4;
    const int oct  = (q & 1) * 8;
    const bool sel = (q < 2);
    const int k0    = (w & 63) * 2;
    const int slice = w >> 6;
    const int i0    = slice * 32;

    const f32x4 zero = {0.f, 0.f, 0.f, 0.f};
    f32x4 acc[2][2];
    float csacc[2][2];
#pragma unroll
    for (int kp = 0; kp < 2; ++kp)
#pragma unroll
        for (int bg = 0; bg < 2; ++bg) { acc[kp][bg] = zero; csacc[kp][bg] = 0.f; }

#pragma unroll 1
    for (int i = i0; i < i0 + 32; ++i) {
        s16x8 X1[2], X2[2];
#pragma unroll
        for (int bg = 0; bg < 2; ++bg)
            pack_A(x + ((size_t)(bg * 16 + n) * 2048 + i) * 16 + oct, X1[bg], X2[bg]);
#pragma unroll
        for (int kp = 0; kp < 2; ++kp) {
            const int k = k0 + kp;
            const s16x8 Wf = pack_B(W + (size_t)i * 32768 + (size_t)k * 256 + n * 16 + oct, sel);
#pragma unroll
            for (int bg = 0; bg < 2; ++bg) {
                if (USE_P) {
                    f32x4 u = __builtin_amdgcn_mfma_f32_16x16x32_bf16(Wf, X1[bg], zero, 0, 0, 0);
                    u       = __builtin_amdgcn_mfma_f32_16x16x32_bf16(Wf, X2[bg], u,    0, 0, 0);
                    const float pv = p[((size_t)i * 128 + k) * 32 + bg * 16 + n];
                    acc[kp][bg].x = fmaf(pv, u.x, acc[kp][bg].x);
                    acc[kp][bg].y = fmaf(pv, u.y, acc[kp][bg].y);
                    acc[kp][bg].z = fmaf(pv, u.z, acc[kp][bg].z);
                    acc[kp][bg].w = fmaf(pv, u.w, acc[kp][bg].w);
                    csacc[kp][bg] += pv;
                } else {
                    acc[kp][bg] = __builtin_amdgcn_mfma_f32_16x16x32_bf16(Wf, X1[bg], acc[kp][bg], 0, 0, 0);
                    acc[kp][bg] = __builtin_amdgcn_mfma_f32_16x16x32_bf16(Wf, X2[bg], acc[kp][bg], 0, 0, 0);
                }
            }
        }
    }
#pragma unroll
    for (int kp = 0; kp < 2; ++kp)
#pragma unroll
        for (int bg = 0; bg < 2; ++bg)
            *(f32x4*)(out_sl + (((size_t)slice * 32 + bg * 16 + n) * 128 + (k0 + kp)) * 16 + 4 * q)
                = acc[kp][bg];
    if (USE_P && lane < 16) {
#pragma unroll
        for (int kp = 0; kp < 2; ++kp)
#pragma unroll
            for (int bg = 0; bg < 2; ++bg)
                csl[((size_t)slice * 128 + (k0 + kp)) * 32 + bg * 16 + n] = csacc[kp][bg];
    }
}

__global__ __launch_bounds__(512) void k_logits_fb(const float* __restrict__ W,
                                                   const float* __restrict__ x,
                                                   const float* __restrict__ Vq,
                                                   const float* __restrict__ Nt,
                                                   const float T,
                                                   float* __restrict__ pbuf)
{
    __shared__ __align__(16) float e_s[8][16][32];
    __shared__ __align__(16) float den_s[8][32];
    __shared__ float denom_s[32];
    const int tid  = threadIdx.x;
    const int wv   = tid >> 6, lane = tid & 63;
    const int n    = lane & 15, q = lane >> 4;
    const int oct  = (q & 1) * 8;
    const bool sel = (q < 2);
    const f32x4 zero = {0.f, 0.f, 0.f, 0.f};
    const int pk = tid >> 2;
    const int pb = (tid & 3) * 8;

    const int i0 = blockIdx.x * 4;
#pragma unroll 1
    for (int ii = 0; ii < 4; ++ii) {
        const int i = i0 + ii;
        s16x8 X1[2], X2[2];
#pragma unroll
        for (int bg = 0; bg < 2; ++bg)
            pack_A(x + ((size_t)(bg * 16 + n) * 2048 + i) * 16 + oct, X1[bg], X2[bg]);

        float den0 = 0.f, den1 = 0.f;
#pragma unroll
        for (int kp = 0; kp < 16; ++kp) {
            const int k = wv * 16 + kp;
            const s16x8 Wf = pack_B(W + (size_t)i * 32768 + (size_t)k * 256 + n * 16 + oct, sel);
            float ebg[2];
#pragma unroll
            for (int bg = 0; bg < 2; ++bg) {
                f32x4 u = __builtin_amdgcn_mfma_f32_16x16x32_bf16(Wf, X1[bg], zero, 0, 0, 0);
                u       = __builtin_amdgcn_mfma_f32_16x16x32_bf16(Wf, X2[bg], u,    0, 0, 0);
                const float4 Vv = *(const float4*)(Vq + (((size_t)k * 4 + q) * 32 + bg * 16 + n) * 4);
                float s2 = u.x * u.x;
                s2 = fmaf(u.y, u.y, s2);
                s2 = fmaf(u.z, u.z, s2);
                s2 = fmaf(u.w, u.w, s2);
                float dt = u.x * Vv.x;
                dt = fmaf(u.y, Vv.y, dt);
                dt = fmaf(u.z, Vv.z, dt);
                dt = fmaf(u.w, Vv.w, dt);
                s2 += __shfl_xor(s2, 16, 64);
                s2 += __shfl_xor(s2, 32, 64);
                dt += __shfl_xor(dt, 16, 64);
                dt += __shfl_xor(dt, 32, 64);
                const float Nr  = Nt[(size_t)k * 32 + bg * 16 + n];
                const float inv = 1.0f / (0.5f + s2);
                const float scl = sqrtf(s2) * inv;
                const float fq  = s2 * s2 * inv * inv;
                const float e   = __expf(T * (1.0f - fq) + 2.0f * scl * dt - Nr);
                if (bg == 0) den0 += e; else den1 += e;
                ebg[bg] = e;
            }
            if (lane < 16) {
                e_s[wv][kp][n]      = ebg[0];
                e_s[wv][kp][16 + n] = ebg[1];
            }
        }
        if (lane < 16) {
            den_s[wv][n]      = den0;
            den_s[wv][16 + n] = den1;
        }
        __syncthreads();
        if (tid < 32) {
            float s = 0.f;
#pragma unroll
            for (int w2 = 0; w2 < 8; ++w2) s += den_s[w2][tid];
            denom_s[tid] = s;
        }
        __syncthreads();
        {
            const float4 e0 = *(const float4*)&e_s[pk >> 4][pk & 15][pb];
            const float4 e1 = *(const float4*)&e_s[pk >> 4][pk & 15][pb + 4];
            const float4 d0 = *(const float4*)&denom_s[pb];
            const float4 d1 = *(const float4*)&denom_s[pb + 4];
            float4 p0, p1;
            p0.x = e0.x / d0.x; p0.y = e0.y / d0.y; p0.z = e0.z / d0.z; p0.w = e0.w / d0.w;
            p1.x = e1.x / d1.x; p1.y = e1.y / d1.y; p1.z = e1.z / d1.z; p1.w = e1.w / d1.w;
            *(float4*)(pbuf + ((size_t)i * 128 + pk) * 32 + pb)     = p0;
            *(float4*)(pbuf + ((size_t)i * 128 + pk) * 32 + pb + 4) = p1;
        }
        __syncthreads();
    }
}

// ---------------------------------------------------------------------------
// Sum nslice partials (+ colsum partials) -> v = squash(raw/colsum);
// write transposed tables (mode 0/1) or output (mode 2).
__global__ __launch_bounds__(256) void k_fin(const float* __restrict__ raw_sl,
                                             const float* __restrict__ csl,   // [nslice][k][b]
                                             const float* __restrict__ Vq_prev,
                                             const float* __restrict__ Nt_prev,
                                             float* __restrict__ Vq_out,
                                             float* __restrict__ Nt_out,
                                             float* __restrict__ out,
                                             const int mode,
                                             const int nslice)
{
    const int tid = threadIdx.x;
    const int t   = blockIdx.x * 16 + (tid >> 4);   // (b,k): b=t>>7, k=t&127
    const int d   = tid & 15;
    const int b   = t >> 7, k = t & 127;
    float s = 0.f, cs = 0.f;
    if (mode == 0) {
#pragma unroll 4
        for (int sl = 0; sl < nslice; ++sl) s += raw_sl[(size_t)sl * 65536 + (size_t)t * 16 + d];
    } else {
#pragma unroll 4
        for (int sl = 0; sl < nslice; ++sl) {
            s  += raw_sl[(size_t)sl * 65536 + (size_t)t * 16 + d];
            cs += csl[(size_t)sl * 4096 + k * 32 + b];
        }
    }
    const float invcs = (mode == 0) ? (1.0f / 2048.0f) : 1.0f / cs;
    const float v = s * invcs;
    float s2 = v * v;
#pragma unroll
    for (int m = 1; m < 16; m <<= 1) s2 += __shfl_xor(s2, m, 64);
    const float inv = 1.0f / (0.5f + s2);
    const float scl = sqrtf(s2) * inv;
    const size_t vidx = (((size_t)k * 4 + (d >> 2)) * 32 + b) * 4 + (d & 3);
    if (mode == 0) {
        Vq_out[vidx] = scl * v;
        if (d == 0) Nt_out[(size_t)k * 32 + b] = s2 * scl * scl;
    } else if (mode == 1) {
        Vq_out[vidx] = Vq_prev[vidx] + scl * v;
        if (d == 0) Nt_out[(size_t)k * 32 + b] = Nt_prev[(size_t)k * 32 + b] + s2 * scl * scl;
    } else {
        out[(size_t)t * 16 + d] = scl * v;
        if (d == 0) out[65536 + t] = s2 * inv;   // ||v|| = s2/(0.5+s2)
    }
}

extern "C" void kernel_launch(void* const* d_in, const int* in_sizes, int n_in,
                              void* d_out, int out_size, void* d_ws, size_t ws_size,
                              hipStream_t stream)
{
    const float* x = (const float*)d_in[0];   // [32][2048][16]
    const float* W = (const float*)d_in[3];   // [2048][128][16][16]; labels = arange -> identity

    float* ws    = (float*)d_ws;
    float* Vbt0  = ws;                  // 65536   [k][d>>2][b][d&3]
    float* VSbt  = ws + 65536;          // 65536
    float* N1t   = ws + 131072;         // 4096    [k][b]
    float* N2t   = ws + 135168;         // 4096
    float* csl   = ws + 139264;         // 1048576 (4MB)  [256][k][b]
    float* slces = ws + 1187840;        // 16777216 (67MB) [256][b][k][d]

    s16x8* Wp = (s16x8*)(ws + 17965056);                   // 268MB: 262144*64 frags
    s16x8* xA = (s16x8*)((short*)Wp + (size_t)134217728);  // 16MB
    const size_t needed = (size_t)17965056 * 4
                        + (size_t)134217728 * 2
                        + (size_t)8388608 * 2;
    const bool pk = (ws_size >= needed);

    if (pk) {
        k_packX<<<1024, 256, 0, stream>>>(x, xA);
        // pack W + iter0 (v0 = squash(mean_i u_hat)) in one pass over W (64 slices)
        k_packWacc<<<1024, 256, 0, stream>>>(W, xA, Wp, slces);
        k_fin<<<256, 256, 0, stream>>>(slces, nullptr, nullptr, nullptr, Vbt0, N1t, nullptr, 0, 64);
        // iter 1 (fused logits+acc; 256 chunks)
        k_iter<<<256, 1024, 0, stream>>>(Wp, xA, Vbt0, N1t, 1.0f, slces, csl);
        k_fin<<<256, 256, 0, stream>>>(slces, csl, Vbt0, N1t, VSbt, N2t, nullptr, 1, 256);
        // iter 2: b2 = dd0+dd1 via summed tables VS=v0+v1, N2=||v0||^2+||v1||^2
        k_iter<<<256, 1024, 0, stream>>>(Wp, xA, VSbt, N2t, 2.0f, slces, csl);
        k_fin<<<256, 256, 0, stream>>>(slces, csl, nullptr, nullptr, nullptr, nullptr, (float*)d_out, 2, 256);
    } else {
        // fallback: unfused, in-kernel packing (64 slices; pbuf in the Wp region)
        float* pbuf = (float*)Wp;
        k_acc_fb<false><<<1024, 256, 0, stream>>>(W, x, nullptr, slces, nullptr);
        k_fin<<<256, 256, 0, stream>>>(slces, nullptr, nullptr, nullptr, Vbt0, N1t, nullptr, 0, 64);
        k_logits_fb<<<512, 512, 0, stream>>>(W, x, Vbt0, N1t, 1.0f, pbuf);
        k_acc_fb<true><<<1024, 256, 0, stream>>>(W, x, pbuf, slces, csl);
        k_fin<<<256, 256, 0, stream>>>(slces, csl, Vbt0, N1t, VSbt, N2t, nullptr, 1, 64);
        k_logits_fb<<<512, 512, 0, stream>>>(W, x, VSbt, N2t, 2.0f, pbuf);
        k_acc_fb<true><<<1024, 256, 0, stream>>>(W, x, pbuf, slces, csl);
        k_fin<<<256, 256, 0, stream>>>(slces, csl, nullptr, nullptr, nullptr, nullptr, (float*)d_out, 2, 64);
    }
}

// Round 6
// 825.577 us; speedup vs baseline: 1.5201x; 1.5201x over previous
//
#include <hip/hip_runtime.h>

// B=32, N_IN=2048, K_OUT=128, C=16, D=16, 3 routing iters.
// Packed path:
//   k_packX   : x -> per-lane MFMA A-frags (hi/lo)
//   k_packWacc: W -> per-lane B-frags (Wp) + iter-0 unweighted MFMA accumulation fused.
//   k_iter    : FUSED logits+softmax+weighted-acc. 512 blocks x 1024 thr; block = (chunk c,
//               b-half h): 8 i's, 128 k, 16 b. Wave = 8 k x 1 bg -> acc[8] (32 VGPR, static
//               index ONLY - R5's "#pragma unroll 2" made acc runtime-indexed -> scratch,
//               52 VGPR + 660MB spill traffic). Per i the 8 W-frags are held in registers
//               (Wfs[8]) so sub-B recomputes u with NO Wp re-read (R5 L2-thrashed 2x fetch).
//               e kept in registers (lane's sub-B value == its sub-A value); only the
//               128-k denominator crosses waves (1KB LDS). Twin blocks (bg0/bg1 of a chunk)
//               land on the same XCD via bijective swizzle for the shared Wp read.
//   k_fin     : partial-reduce (nslice: 64 iter0 / 256 k_iter) + squash.
// MFMA hi/lo trick: K=32 packed [c_hi | c_lo] -> 2 MFMAs ~= exact fp32 product.
// Swapped operands (verified R2): u[d][b] = mfma(Wfrag, xfrag); d-reduce = 4 in-lane
// fmas + xor16 + xor32. No atomics anywhere.
// V table stored [k][d>>2][b][d&3] so each lane's 4 d-values load as one float4.
// NOTE: second __launch_bounds__ arg is forbidden (hard VGPR cap -> scratch spills).

typedef __attribute__((ext_vector_type(8))) short  s16x8;
typedef __attribute__((ext_vector_type(4))) float  f32x4;

__device__ __forceinline__ unsigned bf16rn(float f) {
    const unsigned u = __builtin_bit_cast(unsigned, f);
    return (u + 0x7fffu + ((u >> 16) & 1u)) >> 16;
}
__device__ __forceinline__ unsigned pack2rn(float a, float b) {
    return bf16rn(a) | (bf16rn(b) << 16);
}
__device__ __forceinline__ unsigned phi(float a, float b) {
    return (__builtin_bit_cast(unsigned, a) >> 16) | (__builtin_bit_cast(unsigned, b) & 0xffff0000u);
}
__device__ __forceinline__ unsigned plo(float a, float b) {
    const float la = a - __builtin_bit_cast(float, __builtin_bit_cast(unsigned, a) & 0xffff0000u);
    const float lb = b - __builtin_bit_cast(float, __builtin_bit_cast(unsigned, b) & 0xffff0000u);
    return pack2rn(la, lb);
}

__device__ __forceinline__ void pack_A(const float* __restrict__ xp, s16x8& A1, s16x8& A2) {
    const float4 x0 = *(const float4*)xp;
    const float4 x1 = *(const float4*)(xp + 4);
    uint4 h, l;
    h.x = phi(x0.x, x0.y); h.y = phi(x0.z, x0.w);
    h.z = phi(x1.x, x1.y); h.w = phi(x1.z, x1.w);
    l.x = plo(x0.x, x0.y); l.y = plo(x0.z, x0.w);
    l.z = plo(x1.x, x1.y); l.w = plo(x1.z, x1.w);
    A1 = __builtin_bit_cast(s16x8, h);
    A2 = __builtin_bit_cast(s16x8, l);
}

__device__ __forceinline__ s16x8 pack_B_f(const float4 w0, const float4 w1, bool sel) {
    const float f[8] = {w0.x, w0.y, w0.z, w0.w, w1.x, w1.y, w1.z, w1.w};
    float t[8];
#pragma unroll
    for (int j = 0; j < 8; ++j) {
        const float hf = __builtin_bit_cast(float, __builtin_bit_cast(unsigned, f[j]) & 0xffff0000u);
        t[j] = sel ? hf : (f[j] - hf);
    }
    uint4 bw;
    bw.x = pack2rn(t[0], t[1]);
    bw.y = pack2rn(t[2], t[3]);
    bw.z = pack2rn(t[4], t[5]);
    bw.w = pack2rn(t[6], t[7]);
    return __builtin_bit_cast(s16x8, bw);
}
__device__ __forceinline__ s16x8 pack_B(const float* __restrict__ wp, bool sel) {
    return pack_B_f(*(const float4*)wp, *(const float4*)(wp + 4), sel);
}

// ---------------------------------------------------------------------------
__global__ __launch_bounds__(256) void k_packX(const float* __restrict__ x,
                                               s16x8* __restrict__ xA)
{
    const int wid  = blockIdx.x * 4 + (threadIdx.x >> 6);   // 0..4095 = i*2+bg
    const int lane = threadIdx.x & 63;
    const int i  = wid >> 1, bg = wid & 1;
    const int n  = lane & 15, q = lane >> 4;
    const int oct = (q & 1) * 8;
    s16x8 A1, A2;
    pack_A(x + ((size_t)(bg * 16 + n) * 2048 + i) * 16 + oct, A1, A2);
    s16x8* o = xA + ((size_t)wid * 64 + lane) * 2;
    o[0] = A1;
    o[1] = A2;
}

// ---------------------------------------------------------------------------
// Fused W-pack + iter0 accumulation (64 slices of 32 i). Software-pipelined.
__global__ __launch_bounds__(256) void k_packWacc(const float* __restrict__ W,
                                                  const s16x8* __restrict__ xA,
                                                  s16x8* __restrict__ Wp,
                                                  float* __restrict__ out_sl)   // [64][b][k][d]
{
    const int w    = blockIdx.x * 4 + (threadIdx.x >> 6);   // 0..4095
    const int lane = threadIdx.x & 63;
    const int n    = lane & 15;
    const int q    = lane >> 4;
    const int oct  = (q & 1) * 8;
    const bool sel = (q < 2);
    const int k0    = (w & 63) * 2;
    const int slice = w >> 6;
    const int i0    = slice * 32;

    const f32x4 zero = {0.f, 0.f, 0.f, 0.f};
    f32x4 acc[2][2];
#pragma unroll
    for (int kp = 0; kp < 2; ++kp)
#pragma unroll
        for (int bg = 0; bg < 2; ++bg) acc[kp][bg] = zero;

    float4 rw0[2], rw1[2];
    s16x8 X1c[2], X2c[2];
    {
        const float* wp_ = W + (size_t)i0 * 32768 + (size_t)k0 * 256 + n * 16 + oct;
        rw0[0] = *(const float4*)wp_;          rw1[0] = *(const float4*)(wp_ + 4);
        rw0[1] = *(const float4*)(wp_ + 256);  rw1[1] = *(const float4*)(wp_ + 260);
        const s16x8* xp = xA + (size_t)i0 * 256 + (size_t)lane * 2;
        X1c[0] = xp[0];   X2c[0] = xp[1];
        X1c[1] = xp[128]; X2c[1] = xp[129];
    }

#pragma unroll 1
    for (int i = i0; i < i0 + 32; ++i) {
        const int in_ = (i + 1 < i0 + 32) ? i + 1 : i;
        float4 nw0[2], nw1[2];
        s16x8 X1n[2], X2n[2];
        {
            const float* wp_ = W + (size_t)in_ * 32768 + (size_t)k0 * 256 + n * 16 + oct;
            nw0[0] = *(const float4*)wp_;          nw1[0] = *(const float4*)(wp_ + 4);
            nw0[1] = *(const float4*)(wp_ + 256);  nw1[1] = *(const float4*)(wp_ + 260);
            const s16x8* xp = xA + (size_t)in_ * 256 + (size_t)lane * 2;
            X1n[0] = xp[0];   X2n[0] = xp[1];
            X1n[1] = xp[128]; X2n[1] = xp[129];
        }
#pragma unroll
        for (int kp = 0; kp < 2; ++kp) {
            const s16x8 Wf = pack_B_f(rw0[kp], rw1[kp], sel);
            Wp[((size_t)i * 128 + (k0 + kp)) * 64 + lane] = Wf;
#pragma unroll
            for (int bg = 0; bg < 2; ++bg) {
                acc[kp][bg] = __builtin_amdgcn_mfma_f32_16x16x32_bf16(Wf, X1c[bg], acc[kp][bg], 0, 0, 0);
                acc[kp][bg] = __builtin_amdgcn_mfma_f32_16x16x32_bf16(Wf, X2c[bg], acc[kp][bg], 0, 0, 0);
            }
        }
#pragma unroll
        for (int kp = 0; kp < 2; ++kp) { rw0[kp] = nw0[kp]; rw1[kp] = nw1[kp]; }
#pragma unroll
        for (int bg = 0; bg < 2; ++bg) { X1c[bg] = X1n[bg]; X2c[bg] = X2n[bg]; }
    }
#pragma unroll
    for (int kp = 0; kp < 2; ++kp)
#pragma unroll
        for (int bg = 0; bg < 2; ++bg)
            *(f32x4*)(out_sl + (((size_t)slice * 32 + bg * 16 + n) * 128 + (k0 + kp)) * 16 + 4 * q)
                = acc[kp][bg];
}

// ---------------------------------------------------------------------------
// FUSED routing iteration. 512 blocks x 1024 thr.
// Block (c,h): chunk c (i in [8c,8c+8)), b-half h (b in [16h,16h+16)). Wave wv: k in
// [8wv, 8wv+8). acc[8] f32x4 static-indexed. Per i: Wfs[8] cached in regs (one Wp read),
// sub-A computes es[8] + den; LDS reduce -> denom over 128 k; sub-B recomputes u from
// Wfs and accumulates p*u. Writes out_sl[c][b][k][d] and csl[c][k][b].
__global__ __launch_bounds__(1024) void k_iter(const s16x8* __restrict__ Wp,
                                               const s16x8* __restrict__ xA,
                                               const float* __restrict__ Vq,   // [k][d>>2][b][d&3]
                                               const float* __restrict__ Nt,   // [k][b]
                                               const float T,
                                               float* __restrict__ out_sl,     // [256][b][k][d]
                                               float* __restrict__ csl)        // [256][k][b]
{
    __shared__ float den_s[16][16];
    __shared__ float denom_s[16];
    const int tid  = threadIdx.x;
    const int wv   = tid >> 6, lane = tid & 63;
    const int n    = lane & 15, q = lane >> 4;
    const int bid  = blockIdx.x;
    const int c    = (bid & 7) | ((bid >> 4) << 3);   // chunk 0..255 (twins share XCD)
    const int h    = (bid >> 3) & 1;                  // b-half 0/1
    const int i0    = c * 8;
    const int kbase = wv * 8;
    const f32x4 zero = {0.f, 0.f, 0.f, 0.f};

    f32x4 acc[8];
    float cs0[2] = {0.f, 0.f};                        // colsum for kp = 2q+j
#pragma unroll
    for (int kp = 0; kp < 8; ++kp) acc[kp] = zero;

#pragma unroll 1
    for (int ii = 0; ii < 8; ++ii) {
        const int i = i0 + ii;
        const s16x8* xp = xA + (size_t)i * 256 + (size_t)lane * 2;
        const s16x8 X1 = xp[h * 128];
        const s16x8 X2 = xp[h * 128 + 1];
        const s16x8* wrow = Wp + ((size_t)i * 128 + kbase) * 64 + lane;

        s16x8 Wfs[8];
#pragma unroll
        for (int kp = 0; kp < 8; ++kp) Wfs[kp] = wrow[(size_t)kp * 64];

        float es[8];
        float den = 0.f;
        // ---- sub-A: u tiles -> logits e (all in registers) ----
#pragma unroll
        for (int kp = 0; kp < 8; ++kp) {
            const int k = kbase + kp;
            f32x4 u = __builtin_amdgcn_mfma_f32_16x16x32_bf16(Wfs[kp], X1, zero, 0, 0, 0);
            u       = __builtin_amdgcn_mfma_f32_16x16x32_bf16(Wfs[kp], X2, u,    0, 0, 0);
            const float4 Vv = *(const float4*)(Vq + (((size_t)k * 4 + q) * 32 + h * 16 + n) * 4);
            float s2 = u.x * u.x;
            s2 = fmaf(u.y, u.y, s2);
            s2 = fmaf(u.z, u.z, s2);
            s2 = fmaf(u.w, u.w, s2);
            float dt = u.x * Vv.x;
            dt = fmaf(u.y, Vv.y, dt);
            dt = fmaf(u.z, Vv.z, dt);
            dt = fmaf(u.w, Vv.w, dt);
            s2 += __shfl_xor(s2, 16, 64);
            s2 += __shfl_xor(s2, 32, 64);
            dt += __shfl_xor(dt, 16, 64);
            dt += __shfl_xor(dt, 32, 64);
            const float Nr  = Nt[(size_t)k * 32 + h * 16 + n];
            const float inv = 1.0f / (0.5f + s2);
            const float scl = sqrtf(s2) * inv;
            const float fq  = s2 * s2 * inv * inv;
            const float e   = __expf(T * (1.0f - fq) + 2.0f * scl * dt - Nr);
            es[kp] = e;
            den += e;
        }
        if (lane < 16) den_s[wv][n] = den;
        __syncthreads();
        if (tid < 16) {
            float s = 0.f;
#pragma unroll
            for (int w2 = 0; w2 < 16; ++w2) s += den_s[w2][tid];
            denom_s[tid] = s;
        }
        __syncthreads();
        const float inv0 = 1.0f / denom_s[n];
        // ---- sub-B: recompute u from reg-cached Wfs, accumulate p*u ----
#pragma unroll
        for (int kp = 0; kp < 8; ++kp) {
            f32x4 u = __builtin_amdgcn_mfma_f32_16x16x32_bf16(Wfs[kp], X1, zero, 0, 0, 0);
            u       = __builtin_amdgcn_mfma_f32_16x16x32_bf16(Wfs[kp], X2, u,    0, 0, 0);
            const float p = es[kp] * inv0;
            acc[kp].x = fmaf(p, u.x, acc[kp].x);
            acc[kp].y = fmaf(p, u.y, acc[kp].y);
            acc[kp].z = fmaf(p, u.z, acc[kp].z);
            acc[kp].w = fmaf(p, u.w, acc[kp].w);
            if ((kp >> 1) == q) cs0[kp & 1] += p;
        }
        __syncthreads();   // protect den_s before next i overwrites
    }
#pragma unroll
    for (int kp = 0; kp < 8; ++kp)
        *(f32x4*)(out_sl + (((size_t)c * 32 + h * 16 + n) * 128 + (kbase + kp)) * 16 + 4 * q)
            = acc[kp];
#pragma unroll
    for (int j = 0; j < 2; ++j)
        csl[((size_t)c * 128 + kbase + 2 * q + j) * 32 + h * 16 + n] = cs0[j];
}

// ---------------------------------------------------------------------------
// Legacy unfused kernels (fallback path only; in-kernel packing).
template<bool USE_P>
__global__ __launch_bounds__(256) void k_acc_fb(const float* __restrict__ W,
                                                const float* __restrict__ x,
                                                const float* __restrict__ p,
                                                float* __restrict__ out_sl,
                                                float* __restrict__ csl)
{
    const int w    = blockIdx.x * 4 + (threadIdx.x >> 6);
    const int lane = threadIdx.x & 63;
    const int n    = lane & 15;
    const int q    = lane >> 4;
    const int oct  = (q & 1) * 8;
    const bool sel = (q < 2);
    const int k0    = (w & 63) * 2;
    const int slice = w >> 6;
    const int i0    = slice * 32;

    const f32x4 zero = {0.f, 0.f, 0.f, 0.f};
    f32x4 acc[2][2];
    float csacc[2][2];
#pragma unroll
    for (int kp = 0; kp < 2; ++kp)
#pragma unroll
        for (int bg = 0; bg < 2; ++bg) { acc[kp][bg] = zero; csacc[kp][bg] = 0.f; }

#pragma unroll 1
    for (int i = i0; i < i0 + 32; ++i) {
        s16x8 X1[2], X2[2];
#pragma unroll
        for (int bg = 0; bg < 2; ++bg)
            pack_A(x + ((size_t)(bg * 16 + n) * 2048 + i) * 16 + oct, X1[bg], X2[bg]);
#pragma unroll
        for (int kp = 0; kp < 2; ++kp) {
            const int k = k0 + kp;
            const s16x8 Wf = pack_B(W + (size_t)i * 32768 + (size_t)k * 256 + n * 16 + oct, sel);
#pragma unroll
            for (int bg = 0; bg < 2; ++bg) {
                if (USE_P) {
                    f32x4 u = __builtin_amdgcn_mfma_f32_16x16x32_bf16(Wf, X1[bg], zero, 0, 0, 0);
                    u       = __builtin_amdgcn_mfma_f32_16x16x32_bf16(Wf, X2[bg], u,    0, 0, 0);
                    const float pv = p[((size_t)i * 128 + k) * 32 + bg * 16 + n];
                    acc[kp][bg].x = fmaf(pv, u.x, acc[kp][bg].x);
                    acc[kp][bg].y = fmaf(pv, u.y, acc[kp][bg].y);
                    acc[kp][bg].z = fmaf(pv, u.z, acc[kp][bg].z);
                    acc[kp][bg].w = fmaf(pv, u.w, acc[kp][bg].w);
                    csacc[kp][bg] += pv;
                } else {
                    acc[kp][bg] = __builtin_amdgcn_mfma_f32_16x16x32_bf16(Wf, X1[bg], acc[kp][bg], 0, 0, 0);
                    acc[kp][bg] = __builtin_amdgcn_mfma_f32_16x16x32_bf16(Wf, X2[bg], acc[kp][bg], 0, 0, 0);
                }
            }
        }
    }
#pragma unroll
    for (int kp = 0; kp < 2; ++kp)
#pragma unroll
        for (int bg = 0; bg < 2; ++bg)
            *(f32x4*)(out_sl + (((size_t)slice * 32 + bg * 16 + n) * 128 + (k0 + kp)) * 16 + 4 * q)
                = acc[kp][bg];
    if (USE_P && lane < 16) {
#pragma unroll
        for (int kp = 0; kp < 2; ++kp)
#pragma unroll
            for (int bg = 0; bg < 2; ++bg)
                csl[((size_t)slice * 128 + (k0 + kp)) * 32 + bg * 16 + n] = csacc[kp][bg];
    }
}

__global__ __launch_bounds__(512) void k_logits_fb(const float* __restrict__ W,
                                                   const float* __restrict__ x,
                                                   const float* __restrict__ Vq,
                                                   const float* __restrict__ Nt,
                                                   const float T,
                                                   float* __restrict__ pbuf)
{
    __shared__ __align__(16) float e_s[8][16][32];
    __shared__ __align__(16) float den_s[8][32];
    __shared__ float denom_s[32];
    const int tid  = threadIdx.x;
    const int wv   = tid >> 6, lane = tid & 63;
    const int n    = lane & 15, q = lane >> 4;
    const int oct  = (q & 1) * 8;
    const bool sel = (q < 2);
    const f32x4 zero = {0.f, 0.f, 0.f, 0.f};
    const int pk = tid >> 2;
    const int pb = (tid & 3) * 8;

    const int i0 = blockIdx.x * 4;
#pragma unroll 1
    for (int ii = 0; ii < 4; ++ii) {
        const int i = i0 + ii;
        s16x8 X1[2], X2[2];
#pragma unroll
        for (int bg = 0; bg < 2; ++bg)
            pack_A(x + ((size_t)(bg * 16 + n) * 2048 + i) * 16 + oct, X1[bg], X2[bg]);

        float den0 = 0.f, den1 = 0.f;
#pragma unroll
        for (int kp = 0; kp < 16; ++kp) {
            const int k = wv * 16 + kp;
            const s16x8 Wf = pack_B(W + (size_t)i * 32768 + (size_t)k * 256 + n * 16 + oct, sel);
            float ebg[2];
#pragma unroll
            for (int bg = 0; bg < 2; ++bg) {
                f32x4 u = __builtin_amdgcn_mfma_f32_16x16x32_bf16(Wf, X1[bg], zero, 0, 0, 0);
                u       = __builtin_amdgcn_mfma_f32_16x16x32_bf16(Wf, X2[bg], u,    0, 0, 0);
                const float4 Vv = *(const float4*)(Vq + (((size_t)k * 4 + q) * 32 + bg * 16 + n) * 4);
                float s2 = u.x * u.x;
                s2 = fmaf(u.y, u.y, s2);
                s2 = fmaf(u.z, u.z, s2);
                s2 = fmaf(u.w, u.w, s2);
                float dt = u.x * Vv.x;
                dt = fmaf(u.y, Vv.y, dt);
                dt = fmaf(u.z, Vv.z, dt);
                dt = fmaf(u.w, Vv.w, dt);
                s2 += __shfl_xor(s2, 16, 64);
                s2 += __shfl_xor(s2, 32, 64);
                dt += __shfl_xor(dt, 16, 64);
                dt += __shfl_xor(dt, 32, 64);
                const float Nr  = Nt[(size_t)k * 32 + bg * 16 + n];
                const float inv = 1.0f / (0.5f + s2);
                const float scl = sqrtf(s2) * inv;
                const float fq  = s2 * s2 * inv * inv;
                const float e   = __expf(T * (1.0f - fq) + 2.0f * scl * dt - Nr);
                if (bg == 0) den0 += e; else den1 += e;
                ebg[bg] = e;
            }
            if (lane < 16) {
                e_s[wv][kp][n]      = ebg[0];
                e_s[wv][kp][16 + n] = ebg[1];
            }
        }
        if (lane < 16) {
            den_s[wv][n]      = den0;
            den_s[wv][16 + n] = den1;
        }
        __syncthreads();
        if (tid < 32) {
            float s = 0.f;
#pragma unroll
            for (int w2 = 0; w2 < 8; ++w2) s += den_s[w2][tid];
            denom_s[tid] = s;
        }
        __syncthreads();
        {
            const float4 e0 = *(const float4*)&e_s[pk >> 4][pk & 15][pb];
            const float4 e1 = *(const float4*)&e_s[pk >> 4][pk & 15][pb + 4];
            const float4 d0 = *(const float4*)&denom_s[pb];
            const float4 d1 = *(const float4*)&denom_s[pb + 4];
            float4 p0, p1;
            p0.x = e0.x / d0.x; p0.y = e0.y / d0.y; p0.z = e0.z / d0.z; p0.w = e0.w / d0.w;
            p1.x = e1.x / d1.x; p1.y = e1.y / d1.y; p1.z = e1.z / d1.z; p1.w = e1.w / d1.w;
            *(float4*)(pbuf + ((size_t)i * 128 + pk) * 32 + pb)     = p0;
            *(float4*)(pbuf + ((size_t)i * 128 + pk) * 32 + pb + 4) = p1;
        }
        __syncthreads();
    }
}

// ---------------------------------------------------------------------------
// Sum nslice partials (+ colsum partials) -> v = squash(raw/colsum);
// write transposed tables (mode 0/1) or output (mode 2).
__global__ __launch_bounds__(256) void k_fin(const float* __restrict__ raw_sl,
                                             const float* __restrict__ csl,   // [nslice][k][b]
                                             const float* __restrict__ Vq_prev,
                                             const float* __restrict__ Nt_prev,
                                             float* __restrict__ Vq_out,
                                             float* __restrict__ Nt_out,
                                             float* __restrict__ out,
                                             const int mode,
                                             const int nslice)
{
    const int tid = threadIdx.x;
    const int t   = blockIdx.x * 16 + (tid >> 4);   // (b,k): b=t>>7, k=t&127
    const int d   = tid & 15;
    const int b   = t >> 7, k = t & 127;
    float s = 0.f, cs = 0.f;
    if (mode == 0) {
#pragma unroll 4
        for (int sl = 0; sl < nslice; ++sl) s += raw_sl[(size_t)sl * 65536 + (size_t)t * 16 + d];
    } else {
#pragma unroll 4
        for (int sl = 0; sl < nslice; ++sl) {
            s  += raw_sl[(size_t)sl * 65536 + (size_t)t * 16 + d];
            cs += csl[(size_t)sl * 4096 + k * 32 + b];
        }
    }
    const float invcs = (mode == 0) ? (1.0f / 2048.0f) : 1.0f / cs;
    const float v = s * invcs;
    float s2 = v * v;
#pragma unroll
    for (int m = 1; m < 16; m <<= 1) s2 += __shfl_xor(s2, m, 64);
    const float inv = 1.0f / (0.5f + s2);
    const float scl = sqrtf(s2) * inv;
    const size_t vidx = (((size_t)k * 4 + (d >> 2)) * 32 + b) * 4 + (d & 3);
    if (mode == 0) {
        Vq_out[vidx] = scl * v;
        if (d == 0) Nt_out[(size_t)k * 32 + b] = s2 * scl * scl;
    } else if (mode == 1) {
        Vq_out[vidx] = Vq_prev[vidx] + scl * v;
        if (d == 0) Nt_out[(size_t)k * 32 + b] = Nt_prev[(size_t)k * 32 + b] + s2 * scl * scl;
    } else {
        out[(size_t)t * 16 + d] = scl * v;
        if (d == 0) out[65536 + t] = s2 * inv;   // ||v|| = s2/(0.5+s2)
    }
}

extern "C" void kernel_launch(void* const* d_in, const int* in_sizes, int n_in,
                              void* d_out, int out_size, void* d_ws, size_t ws_size,
                              hipStream_t stream)
{
    const float* x = (const float*)d_in[0];   // [32][2048][16]
    const float* W = (const float*)d_in[3];   // [2048][128][16][16]; labels = arange -> identity

    float* ws    = (float*)d_ws;
    float* Vbt0  = ws;                  // 65536   [k][d>>2][b][d&3]
    float* VSbt  = ws + 65536;          // 65536
    float* N1t   = ws + 131072;         // 4096    [k][b]
    float* N2t   = ws + 135168;         // 4096
    float* csl   = ws + 139264;         // 1048576 (4MB)  [256][k][b]
    float* slces = ws + 1187840;        // 16777216 (67MB) [256][b][k][d]

    s16x8* Wp = (s16x8*)(ws + 17965056);                   // 268MB: 262144*64 frags
    s16x8* xA = (s16x8*)((short*)Wp + (size_t)134217728);  // 16MB
    const size_t needed = (size_t)17965056 * 4
                        + (size_t)134217728 * 2
                        + (size_t)8388608 * 2;
    const bool pk = (ws_size >= needed);

    if (pk) {
        k_packX<<<1024, 256, 0, stream>>>(x, xA);
        // pack W + iter0 (v0 = squash(mean_i u_hat)) in one pass over W (64 slices)
        k_packWacc<<<1024, 256, 0, stream>>>(W, xA, Wp, slces);
        k_fin<<<256, 256, 0, stream>>>(slces, nullptr, nullptr, nullptr, Vbt0, N1t, nullptr, 0, 64);
        // iter 1 (fused logits+acc; 256 chunks x 2 b-halves)
        k_iter<<<512, 1024, 0, stream>>>(Wp, xA, Vbt0, N1t, 1.0f, slces, csl);
        k_fin<<<256, 256, 0, stream>>>(slces, csl, Vbt0, N1t, VSbt, N2t, nullptr, 1, 256);
        // iter 2: b2 = dd0+dd1 via summed tables VS=v0+v1, N2=||v0||^2+||v1||^2
        k_iter<<<512, 1024, 0, stream>>>(Wp, xA, VSbt, N2t, 2.0f, slces, csl);
        k_fin<<<256, 256, 0, stream>>>(slces, csl, nullptr, nullptr, nullptr, nullptr, (float*)d_out, 2, 256);
    } else {
        // fallback: unfused, in-kernel packing (64 slices; pbuf in the Wp region)
        float* pbuf = (float*)Wp;
        k_acc_fb<false><<<1024, 256, 0, stream>>>(W, x, nullptr, slces, nullptr);
        k_fin<<<256, 256, 0, stream>>>(slces, nullptr, nullptr, nullptr, Vbt0, N1t, nullptr, 0, 64);
        k_logits_fb<<<512, 512, 0, stream>>>(W, x, Vbt0, N1t, 1.0f, pbuf);
        k_acc_fb<true><<<1024, 256, 0, stream>>>(W, x, pbuf, slces, csl);
        k_fin<<<256, 256, 0, stream>>>(slces, csl, Vbt0, N1t, VSbt, N2t, nullptr, 1, 64);
        k_logits_fb<<<512, 512, 0, stream>>>(W, x, VSbt, N2t, 2.0f, pbuf);
        k_acc_fb<true><<<1024, 256, 0, stream>>>(W, x, pbuf, slces, csl);
        k_fin<<<256, 256, 0, stream>>>(slces, csl, nullptr, nullptr, nullptr, nullptr, (float*)d_out, 2, 64);
    }
}